// Round 4
// baseline (7642.162 us; speedup 1.0000x reference)
//
#include <hip/hip_runtime.h>

#define NB 256   // batch
#define HH 128   // hidden
#define GG 512   // 4*H gate rows

// ---------------------------------------------------------------------------
// Generic fp32 GEMM over (b, ti) rows:
//   C[b, tC0+ti, n] = sum_k A[b, t00+ti+tsh, k] * W[n, k] + b1[n] (+ b2[n])
// Rows with t00+ti+tsh < 0 are treated as zeros (decoder teacher-force shift).
// BM=BN=128, K-slice 16, 256 threads, 8x8 register tile per thread.
// ---------------------------------------------------------------------------
#define BM 128
#define BN 128
#define KS 16
#define LPITCH 132   // padded LDS row pitch (floats), multiple of 4 for b128

__global__ __launch_bounds__(256, 2) void proj_gemm(
    const float* __restrict__ A, long long lda_b, long long lda_t, int t00, int tsh,
    const float* __restrict__ W,
    const float* __restrict__ b1, const float* __restrict__ b2,
    float* __restrict__ C, long long ldc_b, long long ldc_t, int tC0,
    int CH, int K, int N)
{
  __shared__ float As[KS * LPITCH];   // As[k][m] transposed
  __shared__ float Ws[KS * LPITCH];   // Ws[k][n] transposed

  const int tid = threadIdx.x;
  const int tx = tid & 15;
  const int ty = tid >> 4;

  const long long row0 = (long long)blockIdx.x * BM;
  const int nbase = blockIdx.y * BN;

  // ---- global->reg load assignment: thread loads row lr, 8 k's at lks
  const int lr  = tid >> 1;
  const int lks = (tid & 1) * 8;
  const long long lrow = row0 + lr;
  const int lb  = (int)(lrow / CH);
  const int lti = (int)(lrow - (long long)lb * CH);
  const int lt  = t00 + lti + tsh;
  const float* Arow = (lt >= 0) ? (A + (long long)lb * lda_b + (long long)lt * lda_t)
                                : (const float*)nullptr;
  const int ln = nbase + lr;
  const float* Wrow = (ln < N) ? (W + (long long)ln * K) : (const float*)nullptr;

  float acc[8][8];
#pragma unroll
  for (int i = 0; i < 8; ++i)
#pragma unroll
    for (int j = 0; j < 8; ++j) acc[i][j] = 0.f;

  const int nS = (K + KS - 1) / KS;

  float4 ra0 = make_float4(0.f,0.f,0.f,0.f), ra1 = ra0, rw0 = ra0, rw1 = ra0;

  auto loadRegs = [&](int s) {
    const int k0 = s * KS + lks;
    const float4 z = make_float4(0.f, 0.f, 0.f, 0.f);
    ra0 = (Arow && (k0 + 4 <= K)) ? *(const float4*)(Arow + k0)     : z;
    ra1 = (Arow && (k0 + 8 <= K)) ? *(const float4*)(Arow + k0 + 4) : z;
    rw0 = (Wrow && (k0 + 4 <= K)) ? *(const float4*)(Wrow + k0)     : z;
    rw1 = (Wrow && (k0 + 8 <= K)) ? *(const float4*)(Wrow + k0 + 4) : z;
  };

  loadRegs(0);

  for (int s = 0; s < nS; ++s) {
    __syncthreads();   // previous compute done reading LDS
    {
      float av[8] = {ra0.x, ra0.y, ra0.z, ra0.w, ra1.x, ra1.y, ra1.z, ra1.w};
      float wv[8] = {rw0.x, rw0.y, rw0.z, rw0.w, rw1.x, rw1.y, rw1.z, rw1.w};
#pragma unroll
      for (int j = 0; j < 8; ++j) {
        As[(lks + j) * LPITCH + lr] = av[j];
        Ws[(lks + j) * LPITCH + lr] = wv[j];
      }
    }
    __syncthreads();
    if (s + 1 < nS) loadRegs(s + 1);   // overlap next slice's global loads

#pragma unroll
    for (int kk = 0; kk < KS; ++kk) {
      const float* ar = &As[kk * LPITCH];
      const float* wr = &Ws[kk * LPITCH];
      float4 A0 = *(const float4*)(ar + ty * 8);        // broadcast across tx
      float4 A1 = *(const float4*)(ar + ty * 8 + 4);
      float4 W0 = *(const float4*)(wr + tx * 4);        // cols 4tx..4tx+3 (2-way, free)
      float4 W1 = *(const float4*)(wr + 64 + tx * 4);   // cols 64+4tx..
      float am[8] = {A0.x, A0.y, A0.z, A0.w, A1.x, A1.y, A1.z, A1.w};
      float wm[8] = {W0.x, W0.y, W0.z, W0.w, W1.x, W1.y, W1.z, W1.w};
#pragma unroll
      for (int i = 0; i < 8; ++i)
#pragma unroll
        for (int j = 0; j < 8; ++j)
          acc[i][j] = fmaf(am[i], wm[j], acc[i][j]);
    }
  }

  // ---- epilogue
  const bool fullN = (nbase + BN <= N);
#pragma unroll
  for (int i = 0; i < 8; ++i) {
    long long row = row0 + ty * 8 + i;
    int bb = (int)(row / CH);
    int ti = (int)(row - (long long)bb * CH);
    float* crow = C + (long long)bb * ldc_b + (long long)(tC0 + ti) * ldc_t;
    if (fullN) {
      int c0 = nbase + tx * 4;
      int c1 = nbase + 64 + tx * 4;
      const float4 bv0 = *(const float4*)(b1 + c0);
      const float4 bv1 = *(const float4*)(b1 + c1);
      float4 v0 = make_float4(acc[i][0] + bv0.x, acc[i][1] + bv0.y,
                              acc[i][2] + bv0.z, acc[i][3] + bv0.w);
      float4 v1 = make_float4(acc[i][4] + bv1.x, acc[i][5] + bv1.y,
                              acc[i][6] + bv1.z, acc[i][7] + bv1.w);
      if (b2) {
        const float4 c20 = *(const float4*)(b2 + c0);
        const float4 c21 = *(const float4*)(b2 + c1);
        v0.x += c20.x; v0.y += c20.y; v0.z += c20.z; v0.w += c20.w;
        v1.x += c21.x; v1.y += c21.y; v1.z += c21.z; v1.w += c21.w;
      }
      *(float4*)(crow + c0) = v0;
      *(float4*)(crow + c1) = v1;
    } else {
#pragma unroll
      for (int j = 0; j < 8; ++j) {
        int col = nbase + ((j < 4) ? (tx * 4 + j) : (64 + tx * 4 + (j - 4)));
        if (col < N) {
          float bv = b1[col];
          if (b2) bv += b2[col];
          crow[col] = acc[i][j] + bv;
        }
      }
    }
  }
}

// ---------------------------------------------------------------------------
// LSTM recurrence for one layer over a CH-step chunk.
// One block per batch row; 512 threads; thread g owns gate row g of Whh
// (128 fp32 weights in VGPRs, fully unrolled -> static indexing, no scratch).
// h broadcast: each WAVE keeps a private h copy in its own LDS region
// (h_w[wave][128]); the dot-product reads it with uniform-address
// ds_read_b128 (4 h values / instr, broadcast, conflict-free) -> VALU work
// per step is 128 fmacs, no readlanes.
// Cell update is computed redundantly by every lane (lane owns h/c elements
// {2*lane, 2*lane+1} in registers); only the 4 gate activations cross waves,
// via double-buffered act_lds -> exactly ONE barrier per timestep.
// Gate order (PyTorch): rows 0..127=i, 128..255=f, 256..383=g, 384..511=o.
// ---------------------------------------------------------------------------
__device__ __forceinline__ void barrier_lgkm() {
  // lgkm-only barrier: keeps xp global prefetch in flight across steps
  asm volatile("s_waitcnt lgkmcnt(0)\n\ts_barrier" ::: "memory");
}
__device__ __forceinline__ float sigm_fast(float x) {
  float e = __expf(-x);                      // v_exp based
  return __builtin_amdgcn_rcpf(1.f + e);     // ~1ulp, fine vs fp32 tolerance
}
__device__ __forceinline__ float tanh_fast(float x) {
  float e = __expf(2.f * x);                 // inf-safe: x>>0 -> 1, x<<0 -> -1
  return fmaf(-2.f, __builtin_amdgcn_rcpf(e + 1.f), 1.f);
}

__global__ __launch_bounds__(512, 2) void lstm_rec(
    const float* __restrict__ xp,      // [NB, CH, GG] precomputed x-proj (+biases)
    const float* __restrict__ Whh,     // [GG, HH]
    float* __restrict__ h_state,       // [NB, HH]
    float* __restrict__ c_state,       // [NB, HH]
    float* __restrict__ out_seq,       // [NB, CH, HH] or nullptr
    int CH, int init)
{
  // activations, double-buffered; +2 pad per 128-gate group keeps float2 reads
  // 8B-aligned (group bases 0,130,260,390) and stores stride-1 (conflict-free)
  __shared__ float act_lds[2][GG + 8];
  __shared__ float h_w[8][HH];         // per-WAVE private h copy (wave-local)

  const int g = threadIdx.x;
  const int b = blockIdx.x;
  const int lane = g & 63;
  float* const hw = &h_w[g >> 6][0];

  float4 w[32];
  {
    const float4* wr4 = (const float4*)(Whh + (long long)g * HH);
#pragma unroll
    for (int i = 0; i < 32; ++i) w[i] = wr4[i];
  }

  // lane-pair-owned state, replicated in every wave (identical by construction)
  float2 hv, cv;
  if (init) {
    hv = make_float2(0.f, 0.f); cv = make_float2(0.f, 0.f);
  } else {
    hv = *(const float2*)&h_state[b * HH + 2 * lane];
    cv = *(const float2*)&c_state[b * HH + 2 * lane];
  }
  *(float2*)&hw[2 * lane] = hv;        // wave-local publish (no block barrier)

  const float* xpb = xp + (long long)b * CH * GG + g;
  // depth-3 rolling prefetch of the per-step x-projection element
  float xv0 = xpb[0];
  float xv1 = (CH > 1) ? xpb[GG] : 0.f;
  float xv2 = (CH > 2) ? xpb[2 * GG] : 0.f;

  for (int t = 0; t < CH; ++t) {
    float xv3 = (t + 3 < CH) ? xpb[(long long)(t + 3) * GG] : 0.f;  // prefetch

    // gates[g] = xp[b,t,g] + sum_k h[k] * Whh[g,k]
    float a0 = xv0, a1 = 0.f, a2 = 0.f, a3 = 0.f;
#pragma unroll
    for (int q = 0; q < 32; ++q) {          // k = 4q .. 4q+3
      const float4 hq = *(const float4*)&hw[4 * q];  // uniform addr = broadcast
      const float4 wq = w[q];
      a0 = fmaf(hq.x, wq.x, a0);
      a1 = fmaf(hq.y, wq.y, a1);
      a2 = fmaf(hq.z, wq.z, a2);
      a3 = fmaf(hq.w, wq.w, a3);
    }
    const float gate = (a0 + a1) + (a2 + a3);

    const int buf = t & 1;
    const float act = (g >= 2 * HH && g < 3 * HH) ? tanh_fast(gate)
                                                  : sigm_fast(gate);
    act_lds[buf][g + 2 * (g >> 7)] = act;

    barrier_lgkm();   // acts visible; prior-step reads of this buf long drained

    // all lanes update their two owned h/c elements (redundant across waves)
    const int e = 2 * lane;
    const float2 iv = *(const float2*)&act_lds[buf][e];
    const float2 fv = *(const float2*)&act_lds[buf][e + HH + 2];
    const float2 gv = *(const float2*)&act_lds[buf][e + 2 * HH + 4];
    const float2 ov = *(const float2*)&act_lds[buf][e + 3 * HH + 6];
    cv.x = fmaf(fv.x, cv.x, iv.x * gv.x);
    cv.y = fmaf(fv.y, cv.y, iv.y * gv.y);
    hv.x = ov.x * tanh_fast(cv.x);
    hv.y = ov.y * tanh_fast(cv.y);

    *(float2*)&hw[2 * lane] = hv;      // wave-local publish for next step

    if (out_seq && g < 64)
      *(float2*)&out_seq[(long long)b * CH * HH + (long long)t * HH + e] = hv;

    xv0 = xv1; xv1 = xv2; xv2 = xv3;
  }

  if (g < 64) {
    *(float2*)&h_state[b * HH + 2 * lane] = hv;
    *(float2*)&c_state[b * HH + 2 * lane] = cv;
  }
}

// ---------------------------------------------------------------------------
extern "C" void kernel_launch(void* const* d_in, const int* in_sizes, int n_in,
                              void* d_out, int out_size, void* d_ws, size_t ws_size,
                              hipStream_t stream)
{
  (void)in_sizes; (void)n_in; (void)out_size;

  const float* x     = (const float*)d_in[0];
  const float* y     = (const float*)d_in[1];
  const float* eWih0 = (const float*)d_in[2];
  const float* eWhh0 = (const float*)d_in[3];
  const float* ebih0 = (const float*)d_in[4];
  const float* ebhh0 = (const float*)d_in[5];
  const float* eWih1 = (const float*)d_in[6];
  const float* eWhh1 = (const float*)d_in[7];
  const float* ebih1 = (const float*)d_in[8];
  const float* ebhh1 = (const float*)d_in[9];
  const float* dWih0 = (const float*)d_in[10];
  const float* dWhh0 = (const float*)d_in[11];
  const float* dbih0 = (const float*)d_in[12];
  const float* dbhh0 = (const float*)d_in[13];
  const float* dWih1 = (const float*)d_in[14];
  const float* dWhh1 = (const float*)d_in[15];
  const float* dbih1 = (const float*)d_in[16];
  const float* dbhh1 = (const float*)d_in[17];
  const float* fcW   = (const float*)d_in[18];
  const float* fcb   = (const float*)d_in[19];
  float* out = (float*)d_out;

  const int S = 1024;

  // pick largest chunk length CH (divides 1024) whose ws footprint fits.
  // CAPPED at 256: staging set (xp 134MB + seqA/B 67MB) stays L3-resident,
  // turning the xp write->read round trip into Infinity-Cache hits.
  int CH = 16;
  {
    const int cands[5] = {256, 128, 64, 32, 16};
    for (int i = 0; i < 5; ++i) {
      long long need = (long long)NB * cands[i] * 4LL * (GG + HH + HH)  // xp + seqA + seqB
                     + 4LL * NB * HH * 4                                 // h0,c0,h1,c1
                     + 4096;
      if (need <= (long long)ws_size) { CH = cands[i]; break; }
    }
  }
  const int nchunks = S / CH;

  float* xpb  = (float*)d_ws;                          // [NB, CH, GG]
  float* seqA = xpb  + (long long)NB * CH * GG;        // [NB, CH, HH]
  float* seqB = seqA + (long long)NB * CH * HH;        // [NB, CH, HH]
  float* h0s  = seqB + (long long)NB * CH * HH;        // [NB, HH]
  float* c0s  = h0s + NB * HH;
  float* h1s  = c0s + NB * HH;
  float* c1s  = h1s + NB * HH;

  dim3 pgrid((NB * CH) / BM, GG / BN);
  dim3 fgrid((NB * CH) / BM, (200 + BN - 1) / BN);
  dim3 pblk(256);
  dim3 rgrid(NB);
  dim3 rblk(512);

  // ---------------- encoder ----------------
  for (int cidx = 0; cidx < nchunks; ++cidx) {
    int t0 = cidx * CH;
    proj_gemm<<<pgrid, pblk, 0, stream>>>(
        x, (long long)S * 100, 100, t0, 0,
        eWih0, ebih0, ebhh0,
        xpb, (long long)CH * GG, GG, 0, CH, 100, GG);
    lstm_rec<<<rgrid, rblk, 0, stream>>>(xpb, eWhh0, h0s, c0s, seqA, CH, cidx == 0 ? 1 : 0);
    proj_gemm<<<pgrid, pblk, 0, stream>>>(
        seqA, (long long)CH * HH, HH, 0, 0,
        eWih1, ebih1, ebhh1,
        xpb, (long long)CH * GG, GG, 0, CH, HH, GG);
    lstm_rec<<<rgrid, rblk, 0, stream>>>(xpb, eWhh1, h1s, c1s, (float*)nullptr, CH, cidx == 0 ? 1 : 0);
  }

  // ---------------- decoder (teacher-forced) + FC ----------------
  for (int cidx = 0; cidx < nchunks; ++cidx) {
    int t0 = cidx * CH;
    proj_gemm<<<pgrid, pblk, 0, stream>>>(
        y, (long long)S * 200, 200, t0, -1,          // input shifted by one step
        dWih0, dbih0, dbhh0,
        xpb, (long long)CH * GG, GG, 0, CH, 200, GG);
    lstm_rec<<<rgrid, rblk, 0, stream>>>(xpb, dWhh0, h0s, c0s, seqA, CH, 0);
    proj_gemm<<<pgrid, pblk, 0, stream>>>(
        seqA, (long long)CH * HH, HH, 0, 0,
        dWih1, dbih1, dbhh1,
        xpb, (long long)CH * GG, GG, 0, CH, HH, GG);
    lstm_rec<<<rgrid, rblk, 0, stream>>>(xpb, dWhh1, h1s, c1s, seqB, CH, 0);
    proj_gemm<<<fgrid, pblk, 0, stream>>>(
        seqB, (long long)CH * HH, HH, 0, 0,
        fcW, fcb, (const float*)nullptr,
        out, (long long)S * 200, 200, t0, CH, HH, 200);
  }
}